// Round 1
// baseline (344.147 us; speedup 1.0000x reference)
//
#include <hip/hip_runtime.h>

// GAE: advantages/returns via backward linear recurrence.
// B=8192 rows, T=2048 timesteps. One wave (64 lanes) per row; each lane owns
// 32 contiguous timesteps. Affine-segment composition + wave suffix scan.

constexpr float GAMMA_F = 0.99f;
constexpr float GL      = 0.99f * 0.95f;   // gamma * lambda
constexpr int   T_LEN   = 2048;
constexpr int   CHUNK   = 32;              // elements per lane (64*32 = 2048)
constexpr int   WAVES_PER_BLOCK = 4;

constexpr float gl_pow32() {
    double p = 1.0;
    for (int i = 0; i < 32; ++i) p *= (double)GL;
    return (float)p;
}
constexpr float GL32 = gl_pow32();

__global__ __launch_bounds__(256)
void gae_kernel(const float* __restrict__ reward,
                const int*   __restrict__ term,
                const float* __restrict__ value,
                const float* __restrict__ next_value,
                float* __restrict__ adv_out,
                float* __restrict__ ret_out,
                int rows) {
    const int wid  = threadIdx.x >> 6;
    const int lane = threadIdx.x & 63;
    const int row  = blockIdx.x * WAVES_PER_BLOCK + wid;
    if (row >= rows) return;

    const long base = (long)row * T_LEN + lane * CHUNK;

    const float4* r4 = reinterpret_cast<const float4*>(reward + base);
    const int4*   t4 = reinterpret_cast<const int4*>(term + base);
    const float4* v4 = reinterpret_cast<const float4*>(value + base);
    const float4* n4 = reinterpret_cast<const float4*>(next_value + base);

    float d[CHUNK];     // delta_t
    float val[CHUNK];   // value_t (for returns)
    unsigned mask = 0;  // bit i = not_done at chunk element i

    // ---- load + delta (all static indices; stays in registers) ----
#pragma unroll
    for (int k = 0; k < CHUNK / 4; ++k) {
        float4 r  = r4[k];
        int4   tm = t4[k];
        float4 v  = v4[k];
        float4 nv = n4[k];
        float rr[4] = {r.x, r.y, r.z, r.w};
        int   tt[4] = {tm.x, tm.y, tm.z, tm.w};
        float vv[4] = {v.x, v.y, v.z, v.w};
        float nn[4] = {nv.x, nv.y, nv.z, nv.w};
#pragma unroll
        for (int j = 0; j < 4; ++j) {
            const int i = 4 * k + j;
            const float nd = (float)(1 - tt[j]);
            d[i]   = fmaf(GAMMA_F * nd, nn[j], rr[j]) - vv[j];
            val[i] = vv[j];
            mask  |= (tt[j] ? 0u : 1u) << i;
        }
    }

    // ---- phase 1: local backward scan with zero incoming carry ----
    float g = 0.0f;
#pragma unroll
    for (int i = CHUNK - 1; i >= 0; --i) {
        const float c = ((mask >> i) & 1u) ? GL : 0.0f;
        g = fmaf(c, g, d[i]);
    }
    // segment as affine map: g_out = Bc + A * g_in
    float A  = (mask == 0xFFFFFFFFu) ? GL32 : 0.0f;  // prod a_i: exact (a_i in {0, GL})
    float Bc = g;

    // ---- phase 2: wave suffix composition (Kogge-Stone, 6 steps) ----
#pragma unroll
    for (int off = 1; off < 64; off <<= 1) {
        const float A2 = __shfl_down(A, off, 64);
        const float B2 = __shfl_down(Bc, off, 64);
        if (lane + off < 64) {
            Bc = fmaf(A, B2, Bc);   // B before A (uses old A)
            A *= A2;
        }
    }
    float gin = __shfl_down(Bc, 1, 64);  // incoming carry = suffix starting at lane+1
    if (lane == 63) gin = 0.0f;

    // ---- phase 3: re-scan with true carry, write outputs ----
    float4* a4 = reinterpret_cast<float4*>(adv_out + base);
    float4* o4 = reinterpret_cast<float4*>(ret_out + base);
    g = gin;
#pragma unroll
    for (int k = CHUNK / 4 - 1; k >= 0; --k) {
        float ga[4], ra[4];
#pragma unroll
        for (int j = 3; j >= 0; --j) {
            const int i = 4 * k + j;
            const float c = ((mask >> i) & 1u) ? GL : 0.0f;
            g = fmaf(c, g, d[i]);
            ga[j] = g;
            ra[j] = g + val[i];
        }
        a4[k] = make_float4(ga[0], ga[1], ga[2], ga[3]);
        o4[k] = make_float4(ra[0], ra[1], ra[2], ra[3]);
    }
}

extern "C" void kernel_launch(void* const* d_in, const int* in_sizes, int n_in,
                              void* d_out, int out_size, void* d_ws, size_t ws_size,
                              hipStream_t stream) {
    const float* reward     = (const float*)d_in[0];
    const int*   terminated = (const int*)d_in[1];
    const float* value      = (const float*)d_in[2];
    const float* next_value = (const float*)d_in[3];

    const int total = in_sizes[0];        // B * T
    const int rows  = total / T_LEN;      // B

    float* adv = (float*)d_out;
    float* ret = adv + (long)total;

    const int block = 64 * WAVES_PER_BLOCK;
    const int grid  = (rows + WAVES_PER_BLOCK - 1) / WAVES_PER_BLOCK;
    gae_kernel<<<grid, block, 0, stream>>>(reward, terminated, value, next_value,
                                           adv, ret, rows);
}

// Round 5
// 343.456 us; speedup vs baseline: 1.0020x; 1.0020x over previous
//
#include <hip/hip_runtime.h>

// GAE backward linear recurrence, fully-coalesced hierarchical scan.
// One wave per row (B=8192, T=2048). Row is processed as NBLK=4 super-blocks
// of SEG=512 elements, right-to-left. Within a super-block, lane i owns 8
// CONSECUTIVE timesteps (t = c*512 + lane*8), so all global loads/stores are
// contiguous float4 per lane (1 KB per wave instruction, 8 lines). The
// backward scan composes affine segment maps: local 8-elem compose ->
// 64-lane Kogge-Stone suffix compose (shuffles) -> rescan with true carry.
// Super-block carry is a wave-uniform scalar; next block's loads are issued
// before the current block's compute (2-deep pipeline).

constexpr float GAMMA_F = 0.99f;
constexpr float GL      = 0.99f * 0.95f;
constexpr int   T_LEN   = 2048;
constexpr int   PER_LANE = 8;
constexpr int   SEG     = 64 * PER_LANE;   // 512
constexpr int   NBLK    = T_LEN / SEG;     // 4
constexpr int   WPB     = 4;               // waves per block (256 threads)

typedef float  vf4 __attribute__((ext_vector_type(4)));

constexpr float gl_pow8() {
    double p = 1.0;
    for (int i = 0; i < 8; ++i) p *= (double)GL;
    return (float)p;
}
constexpr float GL8 = gl_pow8();

struct Raw {
    float4 r0, r1, v0, v1, n0, n1;
    int4   t0, t1;
};

__device__ inline Raw load_blk(const float* __restrict__ r, const int* __restrict__ t,
                               const float* __restrict__ v, const float* __restrict__ n,
                               long base) {
    Raw x;
    const float4* r4 = reinterpret_cast<const float4*>(r + base);
    const int4*   t4 = reinterpret_cast<const int4*>(t + base);
    const float4* v4 = reinterpret_cast<const float4*>(v + base);
    const float4* n4 = reinterpret_cast<const float4*>(n + base);
    x.r0 = r4[0]; x.r1 = r4[1];
    x.t0 = t4[0]; x.t1 = t4[1];
    x.v0 = v4[0]; x.v1 = v4[1];
    x.n0 = n4[0]; x.n1 = n4[1];
    return x;
}

__device__ inline void st_nt4(float* p, float a, float b, float c, float d) {
    vf4 val = {a, b, c, d};
    __builtin_nontemporal_store(val, reinterpret_cast<vf4*>(p));
}

__global__ __launch_bounds__(256)
void gae_kernel(const float* __restrict__ reward,
                const int*   __restrict__ term,
                const float* __restrict__ value,
                const float* __restrict__ next_value,
                float* __restrict__ adv_out,
                float* __restrict__ ret_out,
                int rows) {
    const int wid  = threadIdx.x >> 6;
    const int lane = threadIdx.x & 63;
    const int row  = blockIdx.x * WPB + wid;
    if (row >= rows) return;

    const long rowbase = (long)row * T_LEN;

    Raw cur = load_blk(reward, term, value, next_value,
                       rowbase + (long)(NBLK - 1) * SEG + lane * PER_LANE);
    float g_carry = 0.0f;

#pragma unroll
    for (int c = NBLK - 1; c >= 0; --c) {
        Raw nxt;
        if (c > 0)
            nxt = load_blk(reward, term, value, next_value,
                           rowbase + (long)(c - 1) * SEG + lane * PER_LANE);

        // ---- unpack + delta ----
        float rr[8] = {cur.r0.x, cur.r0.y, cur.r0.z, cur.r0.w,
                       cur.r1.x, cur.r1.y, cur.r1.z, cur.r1.w};
        int   tt[8] = {cur.t0.x, cur.t0.y, cur.t0.z, cur.t0.w,
                       cur.t1.x, cur.t1.y, cur.t1.z, cur.t1.w};
        float vv[8] = {cur.v0.x, cur.v0.y, cur.v0.z, cur.v0.w,
                       cur.v1.x, cur.v1.y, cur.v1.z, cur.v1.w};
        float nn[8] = {cur.n0.x, cur.n0.y, cur.n0.z, cur.n0.w,
                       cur.n1.x, cur.n1.y, cur.n1.z, cur.n1.w};
        float d[8];
        unsigned mask = 0;
#pragma unroll
        for (int j = 0; j < 8; ++j) {
            const float nd = (float)(1 - tt[j]);
            d[j]  = fmaf(GAMMA_F * nd, nn[j], rr[j]) - vv[j];
            mask |= (tt[j] ? 0u : 1u) << j;
        }

        // ---- local 8-elem suffix compose (zero incoming carry) ----
        float Bc = 0.0f;
#pragma unroll
        for (int j = PER_LANE - 1; j >= 0; --j) {
            const float a = ((mask >> j) & 1u) ? GL : 0.0f;
            Bc = fmaf(a, Bc, d[j]);
        }
        float A = (mask == 0xFFu) ? GL8 : 0.0f;

        // ---- Kogge-Stone suffix compose across 64 lanes ----
#pragma unroll
        for (int off = 1; off < 64; off <<= 1) {
            const float A2 = __shfl_down(A, off, 64);
            const float B2 = __shfl_down(Bc, off, 64);
            if (lane + off < 64) {
                Bc = fmaf(A, B2, Bc);   // uses old A
                A *= A2;
            }
        }

        // incoming carry for this lane = S_{lane+1}(g_carry)
        const float As1 = __shfl_down(A, 1, 64);
        const float Bs1 = __shfl_down(Bc, 1, 64);
        const float gin = (lane == 63) ? g_carry : fmaf(As1, g_carry, Bs1);

        // whole-block map from lane 0 (for next super-block's carry)
        const float A0 = __shfl(A, 0, 64);
        const float B0 = __shfl(Bc, 0, 64);

        // ---- rescan with true carry, write outputs ----
        float g = gin;
        float ga[8], ro[8];
#pragma unroll
        for (int j = PER_LANE - 1; j >= 0; --j) {
            const float a = ((mask >> j) & 1u) ? GL : 0.0f;
            g = fmaf(a, g, d[j]);
            ga[j] = g;
            ro[j] = g + vv[j];
        }
        const long ob = rowbase + (long)c * SEG + lane * PER_LANE;
        st_nt4(adv_out + ob,     ga[0], ga[1], ga[2], ga[3]);
        st_nt4(adv_out + ob + 4, ga[4], ga[5], ga[6], ga[7]);
        st_nt4(ret_out + ob,     ro[0], ro[1], ro[2], ro[3]);
        st_nt4(ret_out + ob + 4, ro[4], ro[5], ro[6], ro[7]);

        g_carry = fmaf(A0, g_carry, B0);
        if (c > 0) cur = nxt;
    }
}

extern "C" void kernel_launch(void* const* d_in, const int* in_sizes, int n_in,
                              void* d_out, int out_size, void* d_ws, size_t ws_size,
                              hipStream_t stream) {
    const float* reward     = (const float*)d_in[0];
    const int*   terminated = (const int*)d_in[1];
    const float* value      = (const float*)d_in[2];
    const float* next_value = (const float*)d_in[3];

    const int total = in_sizes[0];     // B * T
    const int rows  = total / T_LEN;   // B

    float* adv = (float*)d_out;
    float* ret = adv + (long)total;

    const int block = 64 * WPB;
    const int grid  = (rows + WPB - 1) / WPB;
    gae_kernel<<<grid, block, 0, stream>>>(reward, terminated, value, next_value,
                                           adv, ret, rows);
}

// Round 6
// 334.713 us; speedup vs baseline: 1.0282x; 1.0261x over previous
//
#include <hip/hip_runtime.h>

// GAE backward linear recurrence — fully-coalesced, all-loads-upfront scan.
// One wave per row (B=8192, T=2048). Row = NBLK=4 super-blocks of SEG=512;
// within a block, lane owns 8 CONSECUTIVE timesteps -> every global access is
// contiguous float4 per lane (1 KB per wave instruction).
//
// Key change vs prior round: ALL 32 input loads (4 arrays x 4 blocks x 2
// float4) are issued before any use (32 KB in flight per wave) so HBM latency
// is covered by counted-vmcnt progressive drains instead of one full-latency
// stall per block. The 4 blocks' Kogge-Stone suffix composes are independent
// chains interleaved for ILP; cross-block carry composition is register-only.

constexpr float GAMMA_F = 0.99f;
constexpr float GL      = 0.99f * 0.95f;
constexpr int   T_LEN   = 2048;
constexpr int   PER_LANE = 8;
constexpr int   SEG     = 64 * PER_LANE;   // 512
constexpr int   NBLK    = T_LEN / SEG;     // 4
constexpr int   WPB     = 4;               // waves per block (256 threads)

typedef float vf4 __attribute__((ext_vector_type(4)));

constexpr float gl_pow8() {
    double p = 1.0;
    for (int i = 0; i < 8; ++i) p *= (double)GL;
    return (float)p;
}
constexpr float GL8 = gl_pow8();

__device__ inline void st_nt4(float* p, float a, float b, float c, float d) {
    vf4 val = {a, b, c, d};
    __builtin_nontemporal_store(val, reinterpret_cast<vf4*>(p));
}

__global__ __launch_bounds__(256)
void gae_kernel(const float* __restrict__ reward,
                const int*   __restrict__ term,
                const float* __restrict__ value,
                const float* __restrict__ next_value,
                float* __restrict__ adv_out,
                float* __restrict__ ret_out,
                int rows) {
    const int wid  = threadIdx.x >> 6;
    const int lane = threadIdx.x & 63;
    const int row  = blockIdx.x * WPB + wid;
    if (row >= rows) return;

    const long rowbase = (long)row * T_LEN;

    // ---- phase 0: issue ALL loads (independent; 32 KB/wave in flight) ----
    float4 rr4[NBLK][2], vv4[NBLK][2], nn4[NBLK][2];
    int4   tt4[NBLK][2];
#pragma unroll
    for (int b = 0; b < NBLK; ++b) {
        const long base = rowbase + (long)b * SEG + lane * PER_LANE;
        const float4* r4 = reinterpret_cast<const float4*>(reward + base);
        const int4*   t4 = reinterpret_cast<const int4*>(term + base);
        const float4* v4 = reinterpret_cast<const float4*>(value + base);
        const float4* n4 = reinterpret_cast<const float4*>(next_value + base);
        rr4[b][0] = r4[0]; rr4[b][1] = r4[1];
        tt4[b][0] = t4[0]; tt4[b][1] = t4[1];
        vv4[b][0] = v4[0]; vv4[b][1] = v4[1];
        nn4[b][0] = n4[0]; nn4[b][1] = n4[1];
    }

    // ---- phase 1: per-block delta + local 8-elem suffix compose ----
    float    d[NBLK][PER_LANE], vv[NBLK][PER_LANE];
    unsigned mask[NBLK];
    float    A[NBLK], Bc[NBLK];
#pragma unroll
    for (int b = 0; b < NBLK; ++b) {
        const float rr[8] = {rr4[b][0].x, rr4[b][0].y, rr4[b][0].z, rr4[b][0].w,
                             rr4[b][1].x, rr4[b][1].y, rr4[b][1].z, rr4[b][1].w};
        const int   tt[8] = {tt4[b][0].x, tt4[b][0].y, tt4[b][0].z, tt4[b][0].w,
                             tt4[b][1].x, tt4[b][1].y, tt4[b][1].z, tt4[b][1].w};
        const float vvl[8] = {vv4[b][0].x, vv4[b][0].y, vv4[b][0].z, vv4[b][0].w,
                              vv4[b][1].x, vv4[b][1].y, vv4[b][1].z, vv4[b][1].w};
        const float nn[8] = {nn4[b][0].x, nn4[b][0].y, nn4[b][0].z, nn4[b][0].w,
                             nn4[b][1].x, nn4[b][1].y, nn4[b][1].z, nn4[b][1].w};
        unsigned m = 0;
#pragma unroll
        for (int j = 0; j < 8; ++j) {
            const float nd = (float)(1 - tt[j]);
            d[b][j]  = fmaf(GAMMA_F * nd, nn[j], rr[j]) - vvl[j];
            vv[b][j] = vvl[j];
            m |= (tt[j] ? 0u : 1u) << j;
        }
        mask[b] = m;
        float bc = 0.0f;
#pragma unroll
        for (int j = PER_LANE - 1; j >= 0; --j) {
            const float a = ((m >> j) & 1u) ? GL : 0.0f;
            bc = fmaf(a, bc, d[b][j]);
        }
        Bc[b] = bc;
        A[b]  = (m == 0xFFu) ? GL8 : 0.0f;
    }

    // ---- phase 2: Kogge-Stone suffix compose, 4 independent chains ----
#pragma unroll
    for (int off = 1; off < 64; off <<= 1) {
#pragma unroll
        for (int b = 0; b < NBLK; ++b) {
            const float A2 = __shfl_down(A[b], off, 64);
            const float B2 = __shfl_down(Bc[b], off, 64);
            if (lane + off < 64) {
                Bc[b] = fmaf(A[b], B2, Bc[b]);   // uses old A
                A[b] *= A2;
            }
        }
    }

    float As1[NBLK], Bs1[NBLK], A0[NBLK], B0[NBLK];
#pragma unroll
    for (int b = 0; b < NBLK; ++b) {
        As1[b] = __shfl_down(A[b], 1, 64);
        Bs1[b] = __shfl_down(Bc[b], 1, 64);
        A0[b]  = __shfl(A[b], 0, 64);
        B0[b]  = __shfl(Bc[b], 0, 64);
    }

    // ---- phase 3: cross-block carries (block NBLK-1 is latest in time) ----
    float carry[NBLK];
    carry[NBLK - 1] = 0.0f;
#pragma unroll
    for (int b = NBLK - 2; b >= 0; --b)
        carry[b] = fmaf(A0[b + 1], carry[b + 1], B0[b + 1]);

    // ---- phase 4: rescan with true carry, store ----
#pragma unroll
    for (int b = 0; b < NBLK; ++b) {
        float g = (lane == 63) ? carry[b] : fmaf(As1[b], carry[b], Bs1[b]);
        float ga[8], ro[8];
#pragma unroll
        for (int j = PER_LANE - 1; j >= 0; --j) {
            const float a = ((mask[b] >> j) & 1u) ? GL : 0.0f;
            g = fmaf(a, g, d[b][j]);
            ga[j] = g;
            ro[j] = g + vv[b][j];
        }
        const long ob = rowbase + (long)b * SEG + lane * PER_LANE;
        st_nt4(adv_out + ob,     ga[0], ga[1], ga[2], ga[3]);
        st_nt4(adv_out + ob + 4, ga[4], ga[5], ga[6], ga[7]);
        st_nt4(ret_out + ob,     ro[0], ro[1], ro[2], ro[3]);
        st_nt4(ret_out + ob + 4, ro[4], ro[5], ro[6], ro[7]);
    }
}

extern "C" void kernel_launch(void* const* d_in, const int* in_sizes, int n_in,
                              void* d_out, int out_size, void* d_ws, size_t ws_size,
                              hipStream_t stream) {
    const float* reward     = (const float*)d_in[0];
    const int*   terminated = (const int*)d_in[1];
    const float* value      = (const float*)d_in[2];
    const float* next_value = (const float*)d_in[3];

    const int total = in_sizes[0];     // B * T
    const int rows  = total / T_LEN;   // B

    float* adv = (float*)d_out;
    float* ret = adv + (long)total;

    const int block = 64 * WPB;
    const int grid  = (rows + WPB - 1) / WPB;
    gae_kernel<<<grid, block, 0, stream>>>(reward, terminated, value, next_value,
                                           adv, ret, rows);
}

// Round 7
// 318.638 us; speedup vs baseline: 1.0801x; 1.0505x over previous
//
#include <hip/hip_runtime.h>

// GAE backward linear recurrence — fully-coalesced, all-loads-upfront scan.
// One wave per row (B=8192, T=2048). Row = NBLK=4 super-blocks of SEG=512;
// within a block, lane owns 8 CONSECUTIVE timesteps -> every global access is
// contiguous float4 per lane (1 KB per wave instruction; per input array the
// wave streams its full 8 KB row contiguously).
//
// R6->R7 single-variable change: nontemporal stores -> PLAIN cached stores.
// Rationale: NT stores bypass L2 write-combining; plain full-line wave
// stores let TCC write-allocate without RFO fetch (R6's FETCH_SIZE ~= output
// size suggests ownership fetches on the poisoned output lines).

constexpr float GAMMA_F = 0.99f;
constexpr float GL      = 0.99f * 0.95f;
constexpr int   T_LEN   = 2048;
constexpr int   PER_LANE = 8;
constexpr int   SEG     = 64 * PER_LANE;   // 512
constexpr int   NBLK    = T_LEN / SEG;     // 4
constexpr int   WPB     = 4;               // waves per block (256 threads)

constexpr float gl_pow8() {
    double p = 1.0;
    for (int i = 0; i < 8; ++i) p *= (double)GL;
    return (float)p;
}
constexpr float GL8 = gl_pow8();

__global__ __launch_bounds__(256)
void gae_kernel(const float* __restrict__ reward,
                const int*   __restrict__ term,
                const float* __restrict__ value,
                const float* __restrict__ next_value,
                float* __restrict__ adv_out,
                float* __restrict__ ret_out,
                int rows) {
    const int wid  = threadIdx.x >> 6;
    const int lane = threadIdx.x & 63;
    const int row  = blockIdx.x * WPB + wid;
    if (row >= rows) return;

    const long rowbase = (long)row * T_LEN;

    // ---- phase 0: issue ALL loads (independent; 32 KB/wave in flight) ----
    float4 rr4[NBLK][2], vv4[NBLK][2], nn4[NBLK][2];
    int4   tt4[NBLK][2];
#pragma unroll
    for (int b = 0; b < NBLK; ++b) {
        const long base = rowbase + (long)b * SEG + lane * PER_LANE;
        const float4* r4 = reinterpret_cast<const float4*>(reward + base);
        const int4*   t4 = reinterpret_cast<const int4*>(term + base);
        const float4* v4 = reinterpret_cast<const float4*>(value + base);
        const float4* n4 = reinterpret_cast<const float4*>(next_value + base);
        rr4[b][0] = r4[0]; rr4[b][1] = r4[1];
        tt4[b][0] = t4[0]; tt4[b][1] = t4[1];
        vv4[b][0] = v4[0]; vv4[b][1] = v4[1];
        nn4[b][0] = n4[0]; nn4[b][1] = n4[1];
    }

    // ---- phase 1: per-block delta + local 8-elem suffix compose ----
    float    d[NBLK][PER_LANE], vv[NBLK][PER_LANE];
    unsigned mask[NBLK];
    float    A[NBLK], Bc[NBLK];
#pragma unroll
    for (int b = 0; b < NBLK; ++b) {
        const float rr[8] = {rr4[b][0].x, rr4[b][0].y, rr4[b][0].z, rr4[b][0].w,
                             rr4[b][1].x, rr4[b][1].y, rr4[b][1].z, rr4[b][1].w};
        const int   tt[8] = {tt4[b][0].x, tt4[b][0].y, tt4[b][0].z, tt4[b][0].w,
                             tt4[b][1].x, tt4[b][1].y, tt4[b][1].z, tt4[b][1].w};
        const float vvl[8] = {vv4[b][0].x, vv4[b][0].y, vv4[b][0].z, vv4[b][0].w,
                              vv4[b][1].x, vv4[b][1].y, vv4[b][1].z, vv4[b][1].w};
        const float nn[8] = {nn4[b][0].x, nn4[b][0].y, nn4[b][0].z, nn4[b][0].w,
                             nn4[b][1].x, nn4[b][1].y, nn4[b][1].z, nn4[b][1].w};
        unsigned m = 0;
#pragma unroll
        for (int j = 0; j < 8; ++j) {
            const float nd = (float)(1 - tt[j]);
            d[b][j]  = fmaf(GAMMA_F * nd, nn[j], rr[j]) - vvl[j];
            vv[b][j] = vvl[j];
            m |= (tt[j] ? 0u : 1u) << j;
        }
        mask[b] = m;
        float bc = 0.0f;
#pragma unroll
        for (int j = PER_LANE - 1; j >= 0; --j) {
            const float a = ((m >> j) & 1u) ? GL : 0.0f;
            bc = fmaf(a, bc, d[b][j]);
        }
        Bc[b] = bc;
        A[b]  = (m == 0xFFu) ? GL8 : 0.0f;
    }

    // ---- phase 2: Kogge-Stone suffix compose, 4 independent chains ----
#pragma unroll
    for (int off = 1; off < 64; off <<= 1) {
#pragma unroll
        for (int b = 0; b < NBLK; ++b) {
            const float A2 = __shfl_down(A[b], off, 64);
            const float B2 = __shfl_down(Bc[b], off, 64);
            if (lane + off < 64) {
                Bc[b] = fmaf(A[b], B2, Bc[b]);   // uses old A
                A[b] *= A2;
            }
        }
    }

    float As1[NBLK], Bs1[NBLK], A0[NBLK], B0[NBLK];
#pragma unroll
    for (int b = 0; b < NBLK; ++b) {
        As1[b] = __shfl_down(A[b], 1, 64);
        Bs1[b] = __shfl_down(Bc[b], 1, 64);
        A0[b]  = __shfl(A[b], 0, 64);
        B0[b]  = __shfl(Bc[b], 0, 64);
    }

    // ---- phase 3: cross-block carries (block NBLK-1 is latest in time) ----
    float carry[NBLK];
    carry[NBLK - 1] = 0.0f;
#pragma unroll
    for (int b = NBLK - 2; b >= 0; --b)
        carry[b] = fmaf(A0[b + 1], carry[b + 1], B0[b + 1]);

    // ---- phase 4: rescan with true carry, store (plain cached stores) ----
#pragma unroll
    for (int b = 0; b < NBLK; ++b) {
        float g = (lane == 63) ? carry[b] : fmaf(As1[b], carry[b], Bs1[b]);
        float ga[8], ro[8];
#pragma unroll
        for (int j = PER_LANE - 1; j >= 0; --j) {
            const float a = ((mask[b] >> j) & 1u) ? GL : 0.0f;
            g = fmaf(a, g, d[b][j]);
            ga[j] = g;
            ro[j] = g + vv[b][j];
        }
        const long ob = rowbase + (long)b * SEG + lane * PER_LANE;
        float4* a4 = reinterpret_cast<float4*>(adv_out + ob);
        float4* o4 = reinterpret_cast<float4*>(ret_out + ob);
        a4[0] = make_float4(ga[0], ga[1], ga[2], ga[3]);
        a4[1] = make_float4(ga[4], ga[5], ga[6], ga[7]);
        o4[0] = make_float4(ro[0], ro[1], ro[2], ro[3]);
        o4[1] = make_float4(ro[4], ro[5], ro[6], ro[7]);
    }
}

extern "C" void kernel_launch(void* const* d_in, const int* in_sizes, int n_in,
                              void* d_out, int out_size, void* d_ws, size_t ws_size,
                              hipStream_t stream) {
    const float* reward     = (const float*)d_in[0];
    const int*   terminated = (const int*)d_in[1];
    const float* value      = (const float*)d_in[2];
    const float* next_value = (const float*)d_in[3];

    const int total = in_sizes[0];     // B * T
    const int rows  = total / T_LEN;   // B

    float* adv = (float*)d_out;
    float* ret = adv + (long)total;

    const int block = 64 * WPB;
    const int grid  = (rows + WPB - 1) / WPB;
    gae_kernel<<<grid, block, 0, stream>>>(reward, terminated, value, next_value,
                                           adv, ret, rows);
}